// Round 7
// baseline (115.633 us; speedup 1.0000x reference)
//
#include <hip/hip_runtime.h>

// Fused iterated 3x3 median blur (edge-replicate), up to 9 iterations.
//
// R7: even-aligned LDS geometry + named-scalar stage + runtime k-loop.
//  - R6 diagnosis: all patch multipliers even -> 64 lanes confined to 16
//    even banks -> structural 4-way on every scalar DS op (22.8k conflict
//    cy/CU = 21% of wall), vb odd -> no vectorized perimeter ops. DS unit
//    (per-CU) ~43k cy of the 108k-cy wall.
//  - Fix: halo RAD=10, tile 52x52 @ stride 54, region [2,49]^2, ring at
//    row/col 1 & 50 -> ub,vb = 2+6*{pty,ptx} EVEN. A/bottom rows = 5xb64
//    (uniform 4-per-even-bank-pair = b64 conflict-free minimum), sides =
//    b64 pairs, perimeter rows = 3xb64. Validity [1+k,50-k], k=9 ->
//    [10,41] = output tile.
//  - stage = 36 NAMED floats (R5 proved arrays under a runtime k-loop get
//    demoted to scratch; R6's full unroll fixed that but left 9x ~4KB
//    specializations). One small runtime-T body (~3.5KB, I$-friendly).
//  - All DS reads hoisted to body top; interior published once post-loop.
// One wave per block owns a 32x32 output tile; 11.2KB LDS -> 14 blocks/CU.

#define TD  54
#define RR  52
#define RAD 10
#define NT  64

static __device__ __forceinline__ float min3f(float a, float b, float c) { return fminf(fminf(a, b), c); }
static __device__ __forceinline__ float max3f(float a, float b, float c) { return fmaxf(fmaxf(a, b), c); }
static __device__ __forceinline__ float med3f(float a, float b, float c) { return __builtin_amdgcn_fmed3f(a, b, c); }

// median-of-9 step: inputs rows A0..A7, B0..B7, C0..C7 (8 vertical triples),
// writes 6 outputs, rolls A<-B<-C. Old B values survive in A for next step.
#define MEDSTEP(O0,O1,O2,O3,O4,O5) { \
    float lo0=min3f(A0,B0,C0), mi0=med3f(A0,B0,C0), hi0=max3f(A0,B0,C0); \
    float lo1=min3f(A1,B1,C1), mi1=med3f(A1,B1,C1), hi1=max3f(A1,B1,C1); \
    float lo2=min3f(A2,B2,C2), mi2=med3f(A2,B2,C2), hi2=max3f(A2,B2,C2); \
    float lo3=min3f(A3,B3,C3), mi3=med3f(A3,B3,C3), hi3=max3f(A3,B3,C3); \
    float lo4=min3f(A4,B4,C4), mi4=med3f(A4,B4,C4), hi4=max3f(A4,B4,C4); \
    float lo5=min3f(A5,B5,C5), mi5=med3f(A5,B5,C5), hi5=max3f(A5,B5,C5); \
    float lo6=min3f(A6,B6,C6), mi6=med3f(A6,B6,C6), hi6=max3f(A6,B6,C6); \
    float lo7=min3f(A7,B7,C7), mi7=med3f(A7,B7,C7), hi7=max3f(A7,B7,C7); \
    O0 = med3f(max3f(lo0,lo1,lo2), med3f(mi0,mi1,mi2), min3f(hi0,hi1,hi2)); \
    O1 = med3f(max3f(lo1,lo2,lo3), med3f(mi1,mi2,mi3), min3f(hi1,hi2,hi3)); \
    O2 = med3f(max3f(lo2,lo3,lo4), med3f(mi2,mi3,mi4), min3f(hi2,hi3,hi4)); \
    O3 = med3f(max3f(lo3,lo4,lo5), med3f(mi3,mi4,mi5), min3f(hi3,hi4,hi5)); \
    O4 = med3f(max3f(lo4,lo5,lo6), med3f(mi4,mi5,mi6), min3f(hi4,hi5,hi6)); \
    O5 = med3f(max3f(lo5,lo6,lo7), med3f(mi5,mi6,mi7), min3f(hi5,hi6,hi7)); \
    A0=B0;A1=B1;A2=B2;A3=B3;A4=B4;A5=B5;A6=B6;A7=B7; \
    B0=C0;B1=C1;B2=C2;B3=C3;B4=C4;B5=C5;B6=C6;B7=C7; }

__global__ __launch_bounds__(NT, 4) void median_fused_kernel(
    const float* __restrict__ src, float* __restrict__ dst,
    const int* __restrict__ t)
{
    __shared__ float buf[RR * TD];    // 52 rows x 54 stride = 11232 B

    const int b   = blockIdx.y;
    const int ty  = blockIdx.x >> 4;
    const int tx  = blockIdx.x & 15;
    const int y0  = ty * 32;
    const int x0  = tx * 32;
    const int tid = threadIdx.x;
    const float* img  = src + (b << 18);
    float*       outb = dst + (b << 18);

    int T = t[b];
    T = min(max(T, 0), 9);

    if (T == 0) {                       // straight vector copy, no LDS
        for (int idx = tid; idx < 256; idx += NT) {   // 32 rows x 8 float4
            int row = idx >> 3, c4 = idx & 7;
            *(float4*)&outb[((y0 + row) << 9) + x0 + (c4 << 2)] =
                *(const float4*)&img[((y0 + row) << 9) + x0 + (c4 << 2)];
        }
        return;
    }

    // ---- load 52x52 halo tile (stride 54), clamped (= replicate pad) ----
    for (int i = tid; i < RR * RR; i += NT) {
        int r = i / RR, c = i - r * RR;
        int gy = min(max(y0 - RAD + r, 0), 511);
        int gx = min(max(x0 - RAD + c, 0), 511);
        buf[r * TD + c] = img[(gy << 9) + gx];
    }

    // lane -> 6x6 patch of compute region [2,49]^2 (ring = row/col 1 & 50)
    const int ptx = tid & 7;            // 8 col groups x 6
    const int pty = tid >> 3;           // 8 row groups x 6
    const int ub  = 2 + 6 * pty;        // patch rows [ub, ub+5], EVEN
    const int vb  = 2 + 6 * ptx;        // patch cols [vb, vb+5], EVEN

    // pad-owning lanes (tile row r <-> image row y0-10+r):
    //  y0==0  : image row 0 = r=10 (pty=1,i=2); pad r=9 -> i=1 <- i=2
    //  y0==480: image row 511 = r=41 (pty=6,i=3); pad r=42 -> i=4 <- i=3
    const bool padTop = (y0 == 0)   && (pty == 1);
    const bool padBot = (y0 == 480) && (pty == 6);
    const bool padLft = (x0 == 0)   && (ptx == 1);
    const bool padRgt = (x0 == 480) && (ptx == 6);

    __syncthreads();                    // single-wave: near-free

    // ---- preload own 6x6 patch into 36 NAMED registers ----
    float s00,s01,s02,s03,s04,s05, s10,s11,s12,s13,s14,s15,
          s20,s21,s22,s23,s24,s25, s30,s31,s32,s33,s34,s35,
          s40,s41,s42,s43,s44,s45, s50,s51,s52,s53,s54,s55;
    {
        const float* p = &buf[ub * TD + vb];
        float2 q;
        q=*(const float2*)(p+0); s00=q.x; s01=q.y;
        q=*(const float2*)(p+2); s02=q.x; s03=q.y;
        q=*(const float2*)(p+4); s04=q.x; s05=q.y;  p += TD;
        q=*(const float2*)(p+0); s10=q.x; s11=q.y;
        q=*(const float2*)(p+2); s12=q.x; s13=q.y;
        q=*(const float2*)(p+4); s14=q.x; s15=q.y;  p += TD;
        q=*(const float2*)(p+0); s20=q.x; s21=q.y;
        q=*(const float2*)(p+2); s22=q.x; s23=q.y;
        q=*(const float2*)(p+4); s24=q.x; s25=q.y;  p += TD;
        q=*(const float2*)(p+0); s30=q.x; s31=q.y;
        q=*(const float2*)(p+2); s32=q.x; s33=q.y;
        q=*(const float2*)(p+4); s34=q.x; s35=q.y;  p += TD;
        q=*(const float2*)(p+0); s40=q.x; s41=q.y;
        q=*(const float2*)(p+2); s42=q.x; s43=q.y;
        q=*(const float2*)(p+4); s44=q.x; s45=q.y;  p += TD;
        q=*(const float2*)(p+0); s50=q.x; s51=q.y;
        q=*(const float2*)(p+2); s52=q.x; s53=q.y;
        q=*(const float2*)(p+4); s54=q.x; s55=q.y;
    }

    const int baseA = (ub - 1) * TD + (vb - 2);   // row above, even base
    const int baseG = (ub + 6) * TD + (vb - 2);   // row below, even base

    #pragma unroll 1
    for (int k = 0; k < T; ++k) {
        // ---- hoisted ring reads: all b64, even-aligned, conflict-free ----
        float2 a0 = *(const float2*)&buf[baseA + 0];
        float2 a1 = *(const float2*)&buf[baseA + 2];
        float2 a2 = *(const float2*)&buf[baseA + 4];
        float2 a3 = *(const float2*)&buf[baseA + 6];
        float2 a4 = *(const float2*)&buf[baseA + 8];
        float2 g0 = *(const float2*)&buf[baseG + 0];
        float2 g1 = *(const float2*)&buf[baseG + 2];
        float2 g2 = *(const float2*)&buf[baseG + 4];
        float2 g3 = *(const float2*)&buf[baseG + 6];
        float2 g4 = *(const float2*)&buf[baseG + 8];
        float2 L0 = *(const float2*)&buf[(ub+0)*TD + vb - 2];
        float2 R0 = *(const float2*)&buf[(ub+0)*TD + vb + 6];
        float2 L1 = *(const float2*)&buf[(ub+1)*TD + vb - 2];
        float2 R1 = *(const float2*)&buf[(ub+1)*TD + vb + 6];
        float2 L2 = *(const float2*)&buf[(ub+2)*TD + vb - 2];
        float2 R2 = *(const float2*)&buf[(ub+2)*TD + vb + 6];
        float2 L3 = *(const float2*)&buf[(ub+3)*TD + vb - 2];
        float2 R3 = *(const float2*)&buf[(ub+3)*TD + vb + 6];
        float2 L4 = *(const float2*)&buf[(ub+4)*TD + vb - 2];
        float2 R4 = *(const float2*)&buf[(ub+4)*TD + vb + 6];
        float2 L5 = *(const float2*)&buf[(ub+5)*TD + vb - 2];
        float2 R5 = *(const float2*)&buf[(ub+5)*TD + vb + 6];

        // window rows (8 wide = cols vb-1 .. vb+6)
        float A0=a0.y, A1=a1.x, A2=a1.y, A3=a2.x, A4=a2.y, A5=a3.x, A6=a3.y, A7=a4.x;
        float B0=L0.y, B1=s00, B2=s01, B3=s02, B4=s03, B5=s04, B6=s05, B7=R0.x;
        float C0,C1,C2,C3,C4,C5,C6,C7;

        C0=L1.y; C1=s10; C2=s11; C3=s12; C4=s13; C5=s14; C6=s15; C7=R1.x;
        MEDSTEP(s00,s01,s02,s03,s04,s05)
        C0=L2.y; C1=s20; C2=s21; C3=s22; C4=s23; C5=s24; C6=s25; C7=R2.x;
        MEDSTEP(s10,s11,s12,s13,s14,s15)
        C0=L3.y; C1=s30; C2=s31; C3=s32; C4=s33; C5=s34; C6=s35; C7=R3.x;
        MEDSTEP(s20,s21,s22,s23,s24,s25)
        C0=L4.y; C1=s40; C2=s41; C3=s42; C4=s43; C5=s44; C6=s45; C7=R4.x;
        MEDSTEP(s30,s31,s32,s33,s34,s35)
        C0=L5.y; C1=s50; C2=s51; C3=s52; C4=s53; C5=s54; C6=s55; C7=R5.x;
        MEDSTEP(s40,s41,s42,s43,s44,s45)
        C0=g0.y; C1=g1.x; C2=g1.y; C3=g2.x; C4=g2.y; C5=g3.x; C6=g3.y; C7=g4.x;
        MEDSTEP(s50,s51,s52,s53,s54,s55)

        // register pad fixups (row fix first, then col fix -> corners exact)
        if (padTop) { s10=s20; s11=s21; s12=s22; s13=s23; s14=s24; s15=s25; }
        if (padBot) { s40=s30; s41=s31; s42=s32; s43=s33; s44=s34; s45=s35; }
        if (padLft) { s01=s02; s11=s12; s21=s22; s31=s32; s41=s42; s51=s52; }
        if (padRgt) { s04=s03; s14=s13; s24=s23; s34=s33; s44=s43; s54=s53; }

        __syncthreads();                // all ring reads of state k done (WAR)

        // ---- publish 20-cell perimeter: rows 0,5 as 3xb64, sides scalar ----
        {
            float* w = &buf[ub * TD + vb];
            *(float2*)(w+0) = make_float2(s00, s01);
            *(float2*)(w+2) = make_float2(s02, s03);
            *(float2*)(w+4) = make_float2(s04, s05);
        }
        {
            float* w = &buf[(ub + 5) * TD + vb];
            *(float2*)(w+0) = make_float2(s50, s51);
            *(float2*)(w+2) = make_float2(s52, s53);
            *(float2*)(w+4) = make_float2(s54, s55);
        }
        { float* w = &buf[(ub+1)*TD + vb]; w[0] = s10; w[5] = s15; }
        { float* w = &buf[(ub+2)*TD + vb]; w[0] = s20; w[5] = s25; }
        { float* w = &buf[(ub+3)*TD + vb]; w[0] = s30; w[5] = s35; }
        { float* w = &buf[(ub+4)*TD + vb]; w[0] = s40; w[5] = s45; }

        __syncthreads();                // new ring visible (RAW)
    }

    // ---- publish interior rows 1..4 (full rows, 3xb64 each) ----
    {
        float* w = &buf[(ub + 1) * TD + vb];
        *(float2*)(w+0) = make_float2(s10, s11);
        *(float2*)(w+2) = make_float2(s12, s13);
        *(float2*)(w+4) = make_float2(s14, s15);
    }
    {
        float* w = &buf[(ub + 2) * TD + vb];
        *(float2*)(w+0) = make_float2(s20, s21);
        *(float2*)(w+2) = make_float2(s22, s23);
        *(float2*)(w+4) = make_float2(s24, s25);
    }
    {
        float* w = &buf[(ub + 3) * TD + vb];
        *(float2*)(w+0) = make_float2(s30, s31);
        *(float2*)(w+2) = make_float2(s32, s33);
        *(float2*)(w+4) = make_float2(s34, s35);
    }
    {
        float* w = &buf[(ub + 4) * TD + vb];
        *(float2*)(w+0) = make_float2(s40, s41);
        *(float2*)(w+2) = make_float2(s42, s43);
        *(float2*)(w+4) = make_float2(s44, s45);
    }
    __syncthreads();

    // ---- store 32x32 output tile (tile rows/cols 10..41), float4 global ----
    for (int idx = tid; idx < 256; idx += NT) {       // 32 rows x 8 float4
        int row = idx >> 3, c4 = idx & 7;
        const float* s = &buf[(RAD + row) * TD + RAD + (c4 << 2)];
        float2 u = *(const float2*)(s + 0);
        float2 v = *(const float2*)(s + 2);
        float4 o = { u.x, u.y, v.x, v.y };
        *(float4*)&outb[((y0 + row) << 9) + x0 + (c4 << 2)] = o;
    }
}

extern "C" void kernel_launch(void* const* d_in, const int* in_sizes, int n_in,
                              void* d_out, int out_size, void* d_ws, size_t ws_size,
                              hipStream_t stream) {
    const float* x   = (const float*)d_in[0];
    const int*   t   = (const int*)d_in[1];
    float*       out = (float*)d_out;

    dim3 block(NT);
    dim3 grid(256, 32);   // 16x16 tiles of 32 x 32 batches
    median_fused_kernel<<<grid, block, 0, stream>>>(x, out, t);
}